// Round 9
// baseline (670.623 us; speedup 1.0000x reference)
//
#include <hip/hip_runtime.h>
#include <math.h>

// TrittentionCube: B=16, S=512, HID=2048, H=4, D=512 (S==D)
// Round 14: chain exposure fix — 5x above pipe-sum at 2 waves/SIMD. Chain
// goes to 1024 threads / 16 waves (4 waves/SIMD, still 1 block/CU, same
// 133KB Sb, same fetch): each wave owns a 32-col strip, acc[4][1].
// Proj: grid swap so XCD key = bm-tile (A-strip sharers co-XCD: 12MB/XCD/z
// instead of 33MB); schedule byte-identical otherwise.

typedef _Float16 f16;
typedef f16 f16x8 __attribute__((ext_vector_type(8)));
typedef float f32x4 __attribute__((ext_vector_type(4)));
typedef float f32x16 __attribute__((ext_vector_type(16)));

#define SB_STRIDE 520            // chain S-buffer row stride (halfs)
#define QBLK 128
#define CHAIN_LDS (QBLK * SB_STRIDE * 2)   // 133,120 B (Sb only)
#define PROJ_LDS  131072         // 2 x 64KB K-tile buffers

static constexpr float SCALE = 0.04419417382415922f;  // 1/sqrt(512)

// async global->LDS, 16B per lane; LDS dest = wave-uniform base + lane*16
__device__ __forceinline__ void gl_lds16(const f16* g, f16* l)
{
    __builtin_amdgcn_global_load_lds(
        (const __attribute__((address_space(1))) void*)g,
        (__attribute__((address_space(3))) void*)l, 16, 0, 0);
}

// ---------------------------------------------------------------- convert
__global__ __launch_bounds__(256) void conv_f32_f16(const float* __restrict__ src,
                                                    f16* __restrict__ dst, int n)
{
    int i = (blockIdx.x * 256 + threadIdx.x) * 8;
    if (i + 8 <= n) {
        float4 a = *(const float4*)(src + i);
        float4 b = *(const float4*)(src + i + 4);
        f16 o[8] = {(f16)a.x, (f16)a.y, (f16)a.z, (f16)a.w,
                    (f16)b.x, (f16)b.y, (f16)b.z, (f16)b.w};
        *(int4*)(dst + i) = *(int4*)o;
    }
}

// ---------------------------------------------------------------- projections
struct ProjPtrs {
    const f16* W[5];
    const float* bias[5];
    f16* dst[5];
};

// (verified round-5 8-phase schedule; only change: bm on blockIdx.x so the
// XCD key (linear%8 = bx%8) groups A-strip sharers on one XCD)
__global__ __launch_bounds__(512, 2) void proj_f16(const f16* __restrict__ A, ProjPtrs P)
{
    extern __shared__ f16 sm[];          // 2 * 32768 halfs = 128 KB
    const int z = blockIdx.z;
    const f16* __restrict__ W = P.W[z];
    const float* __restrict__ bias = P.bias[z];
    f16* __restrict__ dst = P.dst[z];
    const bool tr = (z == 2) || (z == 4);

    const int t    = threadIdx.x;
    const int lane = t & 63;
    const int wave = t >> 6;
    const int wr   = wave >> 2, wc = wave & 3;
    const int bm = blockIdx.x * 256, bn = blockIdx.y * 256;   // swapped
    const int r16 = lane & 15;
    const int kq  = lane >> 4;           // 0..3

    const f16* gA = A + (size_t)(bm + (wave >> 1) * 16 + r16) * 2048 + ((wave & 1) * 4 + kq) * 8;
    const f16* gB = W + (size_t)(bn + (wave >> 1) * 16 + r16) * 2048 + ((wave & 1) * 4 + kq) * 8;
    const int stoff = wave * 512;        // wave-uniform LDS stage offset (halfs)

#define STG_A(c, h, tt)                                                     \
    {                                                                       \
        f16* d_ = sm + (c) * 32768 + (h) * 8192 + stoff;                    \
        gl_lds16(gA + (size_t)((h) * 128) * 2048 + (tt) * 64, d_);          \
        gl_lds16(gA + (size_t)((h) * 128 + 64) * 2048 + (tt) * 64, d_ + 4096); \
    }
#define STG_B(c, h, tt)                                                     \
    {                                                                       \
        f16* d_ = sm + (c) * 32768 + 16384 + (h) * 8192 + stoff;            \
        gl_lds16(gB + (size_t)((h) * 128) * 2048 + (tt) * 64, d_);          \
        gl_lds16(gB + (size_t)((h) * 128 + 64) * 2048 + (tt) * 64, d_ + 4096); \
    }

    f32x4 acc[8][4];
#pragma unroll
    for (int mf = 0; mf < 8; ++mf)
#pragma unroll
        for (int nf = 0; nf < 4; ++nf)
#pragma unroll
            for (int r = 0; r < 4; ++r) acc[mf][nf][r] = 0.f;

    STG_A(0, 0, 0); STG_A(0, 1, 0); STG_B(0, 0, 0); STG_B(0, 1, 0);
    STG_A(1, 0, 1); STG_A(1, 1, 1);
    asm volatile("s_waitcnt vmcnt(4)" ::: "memory");   // tile 0 landed
    __builtin_amdgcn_s_barrier();
    asm volatile("" ::: "memory");

    const int aoff = kq * 128 + r16 * 8;   // frag-read lane offset (halfs)

    f16x8 af[8][2], bf[4][2];

    for (int kt = 0; kt < 32; ++kt) {
        const int cur = kt & 1, nxt = cur ^ 1;
        const f16* pa = sm + cur * 32768 + wr * 8192 + aoff;
        const f16* pb = sm + cur * 32768 + 16384 + (wc >> 1) * 8192 + (wc & 1) * 4096 + aoff;

        // ---------------- P1: af[0-3], bf[0-1]; stage B0(kt+1); MFMA m0n0
#pragma unroll
        for (int mf = 0; mf < 4; ++mf)
#pragma unroll
            for (int dk = 0; dk < 2; ++dk)
                af[mf][dk] = *(const f16x8*)(pa + mf * 1024 + dk * 512);
#pragma unroll
        for (int nf = 0; nf < 2; ++nf)
#pragma unroll
            for (int dk = 0; dk < 2; ++dk)
                bf[nf][dk] = *(const f16x8*)(pb + nf * 1024 + dk * 512);
        if (kt + 1 < 32) STG_B(nxt, 0, kt + 1);
        asm volatile("" ::: "memory");
        __builtin_amdgcn_s_barrier();
        asm volatile("s_waitcnt lgkmcnt(0)" ::: "memory");
        __builtin_amdgcn_sched_barrier(0);
        __builtin_amdgcn_s_setprio(1);
#pragma unroll
        for (int mf = 0; mf < 4; ++mf)
#pragma unroll
            for (int nf = 0; nf < 2; ++nf)
#pragma unroll
                for (int dk = 0; dk < 2; ++dk)
                    acc[mf][nf] = __builtin_amdgcn_mfma_f32_16x16x32_f16(
                        af[mf][dk], bf[nf][dk], acc[mf][nf], 0, 0, 0);
        __builtin_amdgcn_s_setprio(0);
        asm volatile("" ::: "memory");
        __builtin_amdgcn_s_barrier();
        asm volatile("" ::: "memory");

        // ---------------- P2: af[4-7]; stage B1(kt+1); MFMA m1n0
#pragma unroll
        for (int mf = 4; mf < 8; ++mf)
#pragma unroll
            for (int dk = 0; dk < 2; ++dk)
                af[mf][dk] = *(const f16x8*)(pa + mf * 1024 + dk * 512);
        if (kt + 1 < 32) STG_B(nxt, 1, kt + 1);
        asm volatile("" ::: "memory");
        __builtin_amdgcn_s_barrier();
        asm volatile("s_waitcnt lgkmcnt(0)" ::: "memory");
        __builtin_amdgcn_sched_barrier(0);
        __builtin_amdgcn_s_setprio(1);
#pragma unroll
        for (int mf = 4; mf < 8; ++mf)
#pragma unroll
            for (int nf = 0; nf < 2; ++nf)
#pragma unroll
                for (int dk = 0; dk < 2; ++dk)
                    acc[mf][nf] = __builtin_amdgcn_mfma_f32_16x16x32_f16(
                        af[mf][dk], bf[nf][dk], acc[mf][nf], 0, 0, 0);
        __builtin_amdgcn_s_setprio(0);
        asm volatile("" ::: "memory");
        __builtin_amdgcn_s_barrier();
        asm volatile("" ::: "memory");

        // ---------------- P3: bf[2-3]; stage A0(kt+2); MFMA m0n1
#pragma unroll
        for (int nf = 2; nf < 4; ++nf)
#pragma unroll
            for (int dk = 0; dk < 2; ++dk)
                bf[nf][dk] = *(const f16x8*)(pb + nf * 1024 + dk * 512);
        if (kt + 2 < 32) STG_A(cur, 0, kt + 2);
        asm volatile("" ::: "memory");
        __builtin_amdgcn_s_barrier();
        asm volatile("s_waitcnt lgkmcnt(0)" ::: "memory");
        __builtin_amdgcn_sched_barrier(0);
        __builtin_amdgcn_s_setprio(1);
#pragma unroll
        for (int mf = 0; mf < 4; ++mf)
#pragma unroll
            for (int nf = 2; nf < 4; ++nf)
#pragma unroll
                for (int dk = 0; dk < 2; ++dk)
                    acc[mf][nf] = __builtin_amdgcn_mfma_f32_16x16x32_f16(
                        af[mf][dk], bf[nf][dk], acc[mf][nf], 0, 0, 0);
        __builtin_amdgcn_s_setprio(0);
        asm volatile("" ::: "memory");
        __builtin_amdgcn_s_barrier();
        asm volatile("" ::: "memory");

        // ---------------- P4: stage A1(kt+2); vmcnt; MFMA m1n1
        if (kt + 2 < 32) STG_A(cur, 1, kt + 2);
        if (kt < 30) asm volatile("s_waitcnt vmcnt(4)" ::: "memory");
        else         asm volatile("s_waitcnt vmcnt(0)" ::: "memory");
        __builtin_amdgcn_s_barrier();
        asm volatile("" ::: "memory");
        __builtin_amdgcn_s_setprio(1);
#pragma unroll
        for (int mf = 4; mf < 8; ++mf)
#pragma unroll
            for (int nf = 2; nf < 4; ++nf)
#pragma unroll
                for (int dk = 0; dk < 2; ++dk)
                    acc[mf][nf] = __builtin_amdgcn_mfma_f32_16x16x32_f16(
                        af[mf][dk], bf[nf][dk], acc[mf][nf], 0, 0, 0);
        __builtin_amdgcn_s_setprio(0);
        asm volatile("" ::: "memory");
        __builtin_amdgcn_s_barrier();
        asm volatile("" ::: "memory");
    }
#undef STG_A
#undef STG_B

    // epilogue: C/D mapping col(n)=lane&15, row(m)=(lane>>4)*4+reg
    const int wm = wr * 128, wn = wc * 64;
#pragma unroll
    for (int nf = 0; nf < 4; ++nf) {
        int n = bn + wn + nf * 16 + r16;
        float bb = bias[n];
        int h = n >> 9, d = n & 511;
#pragma unroll
        for (int mf = 0; mf < 8; ++mf) {
            int mbase = bm + wm + mf * 16 + (lane >> 4) * 4;
            int b = mbase >> 9, s0 = mbase & 511;
            if (!tr) {
#pragma unroll
                for (int r = 0; r < 4; ++r)
                    dst[(((size_t)(b * 4 + h)) * 512 + s0 + r) * 512 + d] =
                        (f16)(acc[mf][nf][r] + bb);
            } else {
                f16 pk[4];
#pragma unroll
                for (int r = 0; r < 4; ++r) pk[r] = (f16)(acc[mf][nf][r] + bb);
                *(float2*)(dst + (((size_t)(b * 4 + h)) * 512 + d) * 512 + s0) =
                    *(float2*)pk;
            }
        }
    }
}

// ---------------------------------------------------------------- fused chain
// 1024 threads, 16 waves; wave w owns a 32-col n-strip over ALL 128 rows:
// acc[4] f32x16 (128x32 per wave).  acc = Sb(128xK=512) @ Bsrc^T,
// Bsrc row-major [n][k] (ld=512).  B fragments load DIRECTLY global->VGPR.
// 2-set pipeline, 16 panels fully unrolled (static set indices).
// 4 waves/SIMD = 2x the latency-filling of the 512-thread version.
__device__ __forceinline__ void stage_ntr(const f16* __restrict__ Bsrc,
                                          const f16* __restrict__ Sb,
                                          int t, f32x16 acc[4])
{
    const int lane = t & 63;
    const int wave = t >> 6;          // 0..15
    const int l31  = lane & 31;
    const int l5   = (lane >> 5) * 8;

#pragma unroll
    for (int mt = 0; mt < 4; ++mt)
#pragma unroll
        for (int r = 0; r < 16; ++r) acc[mt][r] = 0.f;

    const f16* b0 = Bsrc + (size_t)(wave * 32 + l31) * 512 + l5;

    f16x8 bfA[2], bfB[2];     // [dkh]

#define LDP(S, pp)                                              \
    do {                                                        \
        S[0] = *(const f16x8*)(b0 + (pp) * 32);                 \
        S[1] = *(const f16x8*)(b0 + (pp) * 32 + 16);            \
    } while (0)

    LDP(bfA, 0);
    LDP(bfB, 1);

#pragma unroll
    for (int p = 0; p < 16; ++p) {
        f16x8 (&S)[2] = (p & 1) ? bfB : bfA;   // static under full unroll
#pragma unroll
        for (int dkh = 0; dkh < 2; ++dkh) {
            f16x8 af0 = *(const f16x8*)(Sb + (size_t)l31 * SB_STRIDE + p * 32 + dkh * 16 + l5);
            f16x8 af1 = *(const f16x8*)(Sb + (size_t)(32 + l31) * SB_STRIDE + p * 32 + dkh * 16 + l5);
            f16x8 af2 = *(const f16x8*)(Sb + (size_t)(64 + l31) * SB_STRIDE + p * 32 + dkh * 16 + l5);
            f16x8 af3 = *(const f16x8*)(Sb + (size_t)(96 + l31) * SB_STRIDE + p * 32 + dkh * 16 + l5);
            acc[0] = __builtin_amdgcn_mfma_f32_32x32x16_f16(af0, S[dkh], acc[0], 0, 0, 0);
            acc[1] = __builtin_amdgcn_mfma_f32_32x32x16_f16(af1, S[dkh], acc[1], 0, 0, 0);
            acc[2] = __builtin_amdgcn_mfma_f32_32x32x16_f16(af2, S[dkh], acc[2], 0, 0, 0);
            acc[3] = __builtin_amdgcn_mfma_f32_32x32x16_f16(af3, S[dkh], acc[3], 0, 0, 0);
        }
        if (p + 2 < 16) LDP(S, p + 2);   // reload just-consumed set for p+2
    }
#undef LDP
}

// C/D mapping 32x32: col=lane&31, row=(reg&3)+8*(reg>>2)+4*(lane>>5)
__device__ __forceinline__ void emit_to_S(f16* __restrict__ Sb, const f32x16 acc[4],
                                          int t, float scale)
{
    const int lane = t & 63;
    const int wn = (t >> 6) * 32;
#pragma unroll
    for (int mt = 0; mt < 4; ++mt) {
        int col = wn + (lane & 31);
#pragma unroll
        for (int r = 0; r < 16; ++r) {
            int row = mt * 32 + (r & 3) + 8 * (r >> 2) + 4 * (lane >> 5);
            Sb[(size_t)row * SB_STRIDE + col] = (f16)(acc[mt][r] * scale);
        }
    }
}

// bhmask/q0shift: bh = bx & bhmask, q0 = (bx >> q0shift) * QBLK.
__global__ __launch_bounds__(1024, 4) void chain_f16(
    const f16* __restrict__ q16, const f16* __restrict__ k16,
    const f16* __restrict__ ck16, const f16* __restrict__ vt16,
    const f16* __restrict__ cvt16, float* __restrict__ out,
    int bhmask, int q0shift)
{
    extern __shared__ f16 smem[];
    f16* Sb = smem;                       // [128][SB_STRIDE] = 133,120 B
    const int t = threadIdx.x;
    const int bh = blockIdx.x & bhmask;
    const int q0 = (blockIdx.x >> q0shift) * QBLK;
    const size_t SB = 512 * 512;

    // stage Q[q0..q0+128) into Sbuf
    const f16* Q = q16 + bh * SB;
    for (int i = t; i < 8192; i += 1024) {
        int row = i >> 6, c = (i & 63) * 8;
        *(int4*)(Sb + (size_t)row * SB_STRIDE + c) =
            *(const int4*)(Q + (size_t)(q0 + row) * 512 + c);
    }
    __syncthreads();

    f32x16 acc[4];

    // S1 = Q @ K^T
    stage_ntr(k16 + bh * SB, Sb, t, acc);
    __syncthreads();                 // all Sb reads done before overwrite
    emit_to_S(Sb, acc, t, 1.0f);
    __syncthreads();

    // S2 = S1 @ CK^T * SCALE
    stage_ntr(ck16 + bh * SB, Sb, t, acc);
    __syncthreads();
    emit_to_S(Sb, acc, t, SCALE);
    __syncthreads();

    // softmax rows (wave w -> rows 8w..8w+8)
    {
        const int lane = t & 63;
        const int wave = t >> 6;
        for (int rr = 0; rr < 8; ++rr) {
            int r = wave * 8 + rr;
            f16x8 xv = *(const f16x8*)(Sb + (size_t)r * SB_STRIDE + lane * 8);
            float x[8];
            float mx = -1e30f;
#pragma unroll
            for (int j = 0; j < 8; ++j) { x[j] = (float)xv[j]; mx = fmaxf(mx, x[j]); }
#pragma unroll
            for (int o = 32; o > 0; o >>= 1) mx = fmaxf(mx, __shfl_xor(mx, o));
            float s = 0.f;
#pragma unroll
            for (int j = 0; j < 8; ++j) { x[j] = __expf(x[j] - mx); s += x[j]; }
#pragma unroll
            for (int o = 32; o > 0; o >>= 1) s += __shfl_xor(s, o);
            float inv = 1.0f / s;
            f16x8 ov;
#pragma unroll
            for (int j = 0; j < 8; ++j) ov[j] = (f16)(x[j] * inv);
            *(f16x8*)(Sb + (size_t)r * SB_STRIDE + lane * 8) = ov;
        }
    }
    __syncthreads();

    // C1 = P @ V   (Vt is [bh][d][s]: NT-ready)
    stage_ntr(vt16 + bh * SB, Sb, t, acc);
    __syncthreads();
    emit_to_S(Sb, acc, t, 1.0f);
    __syncthreads();

    // OUT = C1 @ CV (CVt NT-ready), merge-heads store f32
    stage_ntr(cvt16 + bh * SB, Sb, t, acc);
    {
        const int lane = t & 63;
        const int wn = (t >> 6) * 32;
        int b = bh >> 2, h = bh & 3;
#pragma unroll
        for (int mt = 0; mt < 4; ++mt) {
            int col = h * 512 + wn + (lane & 31);
#pragma unroll
            for (int r = 0; r < 16; ++r) {
                int row = q0 + mt * 32 + (r & 3) + 8 * (r >> 2) + 4 * (lane >> 5);
                out[((size_t)b * 512 + row) * 2048 + col] = acc[mt][r];
            }
        }
    }
}

// ---------------------------------------------------------------- host
extern "C" void kernel_launch(void* const* d_in, const int* in_sizes, int n_in,
                              void* d_out, int out_size, void* d_ws, size_t ws_size,
                              hipStream_t stream)
{
    const float* hs = (const float*)d_in[0];
    const float* Wf[5] = {(const float*)d_in[1], (const float*)d_in[3],
                          (const float*)d_in[5], (const float*)d_in[7],
                          (const float*)d_in[9]};
    const float* bf[5] = {(const float*)d_in[2], (const float*)d_in[4],
                          (const float*)d_in[6], (const float*)d_in[8],
                          (const float*)d_in[10]};
    float* out = (float*)d_out;

    hipFuncSetAttribute((const void*)chain_f16,
                        hipFuncAttributeMaxDynamicSharedMemorySize, CHAIN_LDS);
    hipFuncSetAttribute((const void*)proj_f16,
                        hipFuncAttributeMaxDynamicSharedMemorySize, PROJ_LDS);

    f16* ws = (f16*)d_ws;
    const size_t WELEM = 2048ULL * 2048;      // 4,194,304
    const size_t FULLACT = 64ULL * 512 * 512; // 16,777,216

    f16* W16[5];
    for (int i = 0; i < 5; ++i) W16[i] = ws + i * WELEM;
    f16* after_w = ws + 5 * WELEM;

    for (int i = 0; i < 5; ++i)
        conv_f32_f16<<<dim3(WELEM / 2048), 256, 0, stream>>>(Wf[i], W16[i], (int)WELEM);

    size_t full_need = (5 * WELEM + FULLACT + 5 * FULLACT) * sizeof(f16);  // 243,269,632
    if (ws_size >= full_need) {
        // ---------------- full path ----------------
        f16* hs16 = after_w;
        f16* act[5];
        for (int i = 0; i < 5; ++i) act[i] = after_w + FULLACT + i * FULLACT;

        conv_f32_f16<<<dim3(FULLACT / 2048), 256, 0, stream>>>(hs, hs16, (int)FULLACT);

        ProjPtrs P;
        for (int i = 0; i < 5; ++i) { P.W[i] = W16[i]; P.bias[i] = bf[i]; P.dst[i] = act[i]; }
        proj_f16<<<dim3(32, 8, 5), 512, PROJ_LDS, stream>>>(hs16, P);

        // act order: q,k,v^T,ck,cv^T -> chain(q,k,ck,vt,cvt)
        // 256 blocks: bh = bx & 63 (same XCD for a bh's 4 q0-blocks), q0 = (bx>>6)*128
        chain_f16<<<dim3(256), 1024, CHAIN_LDS, stream>>>(
            act[0], act[1], act[3], act[2], act[4], out, 63, 6);
    } else {
        // ---------------- chunked path (54.5 MB ws) ----------------
        const size_t CHROW = 1048576ULL;      // 512*2048 elems per batch
        const size_t CHACT = 4ULL * 512 * 512;
        f16* hs16c = after_w;
        f16* act[5];
        for (int i = 0; i < 5; ++i) act[i] = after_w + CHROW + i * CHACT;

        ProjPtrs P;
        for (int i = 0; i < 5; ++i) { P.W[i] = W16[i]; P.bias[i] = bf[i]; P.dst[i] = act[i]; }

        for (int c = 0; c < 16; ++c) {
            conv_f32_f16<<<dim3(CHROW / 2048), 256, 0, stream>>>(
                hs + c * CHROW, hs16c, (int)CHROW);
            proj_f16<<<dim3(2, 8, 5), 512, PROJ_LDS, stream>>>(hs16c, P);
            chain_f16<<<dim3(16), 1024, CHAIN_LDS, stream>>>(
                act[0], act[1], act[3], act[2], act[4], out + c * CHROW, 3, 2);
        }
    }

    (void)in_sizes; (void)n_in; (void)out_size;
}